// Round 1
// baseline (266.313 us; speedup 1.0000x reference)
//
#include <hip/hip_runtime.h>
#include <hip/hip_bf16.h>
#include <cstdint>

#define CH 128

// ---------------- CSR build ----------------

__global__ __launch_bounds__(256) void k_zero(int* __restrict__ p, int n) {
  int i = blockIdx.x * 256 + threadIdx.x;
  if (i < n) p[i] = 0;
}

__global__ __launch_bounds__(256) void k_count(const int* __restrict__ dst, int* __restrict__ deg, int E) {
  int i = blockIdx.x * 256 + threadIdx.x;
  if (i < E) atomicAdd(&deg[dst[i]], 1);
}

__global__ __launch_bounds__(256) void k_dinv(const int* __restrict__ deg, float* __restrict__ dinv, int n) {
  int i = blockIdx.x * 256 + threadIdx.x;
  if (i < n) dinv[i] = rsqrtf((float)(deg[i] + 1));  // +1 self-loop
}

// exclusive scan of deg -> row_ptr, 3-kernel hierarchy
__global__ __launch_bounds__(1024) void k_scan1(const int* __restrict__ deg, int* __restrict__ excl,
                                                int* __restrict__ blocksum, int n) {
  __shared__ int sd[1024];
  int tid = threadIdx.x;
  int i = blockIdx.x * 1024 + tid;
  int v = (i < n) ? deg[i] : 0;
  int x = v;
  sd[tid] = x;
  __syncthreads();
  for (int off = 1; off < 1024; off <<= 1) {
    int t = (tid >= off) ? sd[tid - off] : 0;
    __syncthreads();
    x += t;
    sd[tid] = x;
    __syncthreads();
  }
  if (i < n) excl[i] = x - v;
  if (tid == 1023) blocksum[blockIdx.x] = x;
}

__global__ void k_scan2(int* __restrict__ blocksum, int nb) {  // 1 block, 64 threads; nb <= 64
  int lane = threadIdx.x;
  int v = (lane < nb) ? blocksum[lane] : 0;
  int orig = v;
  for (int off = 1; off < 64; off <<= 1) {
    int t = __shfl_up(v, off, 64);
    if (lane >= off) v += t;
  }
  if (lane < nb) blocksum[lane] = v - orig;  // exclusive block offset
}

__global__ __launch_bounds__(256) void k_scan3(int* __restrict__ row_ptr, const int* __restrict__ blockoff,
                                               int* __restrict__ cursor, int n, int E) {
  int i = blockIdx.x * 256 + threadIdx.x;
  if (i < n) {
    int r = row_ptr[i] + blockoff[i >> 10];
    row_ptr[i] = r;
    cursor[i] = r;
  }
  if (i == 0) row_ptr[n] = E;
}

__global__ __launch_bounds__(256) void k_fill(const int* __restrict__ src, const int* __restrict__ dst,
                                              int* __restrict__ cursor, int* __restrict__ csr_src, int E) {
  int i = blockIdx.x * 256 + threadIdx.x;
  if (i < E) {
    int slot = atomicAdd(&cursor[dst[i]], 1);
    csr_src[slot] = src[i];
  }
}

// ---------------- dense GEMM: C[n x 128] = A[n x 128] @ W[128 x 128] ----------------
// block = 256 threads, 32 rows per block; thread = 4 rows x 4 cols register tile.
__global__ __launch_bounds__(256) void k_gemm(const float* __restrict__ A, const float* __restrict__ W,
                                              float* __restrict__ C, int n) {
  __shared__ float sW[CH * CH];   // 64 KB
  __shared__ float sA[32][CH];    // 16 KB
  for (int i = threadIdx.x; i < CH * CH / 4; i += 256)
    *(float4*)&sW[i * 4] = *(const float4*)&W[i * 4];

  int rb = blockIdx.x * 32;
  for (int i = threadIdx.x; i < 32 * 32; i += 256) {
    int r = i >> 5, c4 = (i & 31) << 2;
    int row = rb + r;
    float4 val = (row < n) ? *(const float4*)&A[(size_t)row * CH + c4] : make_float4(0.f, 0.f, 0.f, 0.f);
    *(float4*)&sA[r][c4] = val;
  }
  __syncthreads();

  int tx = threadIdx.x & 31;   // col group: cols tx*4 .. tx*4+3
  int ty = threadIdx.x >> 5;   // row group: rows ty*4 .. ty*4+3
  float acc[4][4] = {};
#pragma unroll 4
  for (int k = 0; k < CH; ++k) {
    float4 w4 = *(const float4*)&sW[k * CH + (tx << 2)];
    float a0 = sA[(ty << 2) + 0][k];
    float a1 = sA[(ty << 2) + 1][k];
    float a2 = sA[(ty << 2) + 2][k];
    float a3 = sA[(ty << 2) + 3][k];
    acc[0][0] += a0 * w4.x; acc[0][1] += a0 * w4.y; acc[0][2] += a0 * w4.z; acc[0][3] += a0 * w4.w;
    acc[1][0] += a1 * w4.x; acc[1][1] += a1 * w4.y; acc[1][2] += a1 * w4.z; acc[1][3] += a1 * w4.w;
    acc[2][0] += a2 * w4.x; acc[2][1] += a2 * w4.y; acc[2][2] += a2 * w4.z; acc[2][3] += a2 * w4.w;
    acc[3][0] += a3 * w4.x; acc[3][1] += a3 * w4.y; acc[3][2] += a3 * w4.z; acc[3][3] += a3 * w4.w;
  }
#pragma unroll
  for (int r = 0; r < 4; ++r) {
    int row = rb + (ty << 2) + r;
    if (row < n) {
      float4 o = make_float4(acc[r][0], acc[r][1], acc[r][2], acc[r][3]);
      *(float4*)&C[(size_t)row * CH + (tx << 2)] = o;
    }
  }
}

// ---------------- aggregation: out[v] = relu(sum_{s->v} h[s]*dinv[s]*dinv[v] + h[v]*dinv[v]^2 + b) ----
// one wave64 per node, 2 channels per lane.
__global__ __launch_bounds__(256) void k_agg(const float* __restrict__ h, const int* __restrict__ row_ptr,
                                             const int* __restrict__ csr_src, const float* __restrict__ dinv,
                                             const float* __restrict__ b, float* __restrict__ out, int n) {
  int gid = blockIdx.x * 256 + threadIdx.x;
  int v = gid >> 6;
  int lane = threadIdx.x & 63;
  if (v >= n) return;
  float dv = dinv[v];
  float self = dv * dv;
  float acc0 = h[(size_t)v * CH + lane] * self;
  float acc1 = h[(size_t)v * CH + 64 + lane] * self;
  int j = row_ptr[v], end = row_ptr[v + 1];
  for (; j + 1 < end; j += 2) {
    int s0 = csr_src[j];
    int s1 = csr_src[j + 1];
    float w0 = dinv[s0] * dv;
    float w1 = dinv[s1] * dv;
    const float* p0 = &h[(size_t)s0 * CH];
    const float* p1 = &h[(size_t)s1 * CH];
    float x00 = p0[lane], x01 = p0[64 + lane];
    float x10 = p1[lane], x11 = p1[64 + lane];
    acc0 += x00 * w0; acc1 += x01 * w0;
    acc0 += x10 * w1; acc1 += x11 * w1;
  }
  if (j < end) {
    int s0 = csr_src[j];
    float w0 = dinv[s0] * dv;
    acc0 += h[(size_t)s0 * CH + lane] * w0;
    acc1 += h[(size_t)s0 * CH + 64 + lane] * w0;
  }
  acc0 += b[lane];
  acc1 += b[64 + lane];
  out[(size_t)v * CH + lane] = fmaxf(acc0, 0.f);
  out[(size_t)v * CH + 64 + lane] = fmaxf(acc1, 0.f);
}

// ---------------- launch ----------------

extern "C" void kernel_launch(void* const* d_in, const int* in_sizes, int n_in,
                              void* d_out, int out_size, void* d_ws, size_t ws_size,
                              hipStream_t stream) {
  const float* x  = (const float*)d_in[0];
  const int*   ei = (const int*)d_in[1];
  const float* W1 = (const float*)d_in[2];
  const float* b1 = (const float*)d_in[3];
  const float* W2 = (const float*)d_in[4];
  const float* b2 = (const float*)d_in[5];
  float* out = (float*)d_out;

  const int N = in_sizes[0] / CH;
  const int E = in_sizes[1] / 2;
  const int* src = ei;
  const int* dst = ei + E;

  char* ws = (char*)d_ws;
  size_t off = 0;
  auto alloc = [&](size_t bytes) -> void* {
    void* p = ws + off;
    off += (bytes + 255) & ~(size_t)255;
    return p;
  };
  int*   deg      = (int*)alloc((size_t)N * 4);
  int*   row_ptr  = (int*)alloc((size_t)(N + 1) * 4);
  int*   cursor   = (int*)alloc((size_t)N * 4);
  int*   csr_src  = (int*)alloc((size_t)E * 4);
  int*   blocksum = (int*)alloc(64 * 4);
  float* dinv     = (float*)alloc((size_t)N * 4);
  float* h        = (float*)alloc((size_t)N * CH * 4);
  (void)ws_size;

  const int gN = (N + 255) / 256;
  const int gE = (E + 255) / 256;
  const int nb = (N + 1023) / 1024;

  k_zero<<<gN, 256, 0, stream>>>(deg, N);
  k_count<<<gE, 256, 0, stream>>>(dst, deg, E);
  k_dinv<<<gN, 256, 0, stream>>>(deg, dinv, N);
  k_scan1<<<nb, 1024, 0, stream>>>(deg, row_ptr, blocksum, N);
  k_scan2<<<1, 64, 0, stream>>>(blocksum, nb);
  k_scan3<<<gN, 256, 0, stream>>>(row_ptr, blocksum, cursor, N, E);
  k_fill<<<gE, 256, 0, stream>>>(src, dst, cursor, csr_src, E);

  const int gG = (N + 31) / 32;
  const int gA = (N + 3) / 4;  // one wave64 per node, 4 waves/block

  // layer 1
  k_gemm<<<gG, 256, 0, stream>>>(x, W1, h, N);
  k_agg<<<gA, 256, 0, stream>>>(h, row_ptr, csr_src, dinv, b1, out, N);
  // layer 2
  k_gemm<<<gG, 256, 0, stream>>>(out, W2, h, N);
  k_agg<<<gA, 256, 0, stream>>>(h, row_ptr, csr_src, dinv, b2, out, N);
}

// Round 2
// 216.832 us; speedup vs baseline: 1.2282x; 1.2282x over previous
//
#include <hip/hip_runtime.h>
#include <hip/hip_bf16.h>
#include <cstdint>

#define CH 128

// ---------------- bf16 helpers ----------------
__device__ __forceinline__ float bf_lo(uint32_t u) { return __uint_as_float(u << 16); }
__device__ __forceinline__ float bf_hi(uint32_t u) { return __uint_as_float(u & 0xffff0000u); }
__device__ __forceinline__ uint32_t f2bf(float f) {  // round-to-nearest-even, returns in low 16
  uint32_t u = __float_as_uint(f);
  u += 0x7fff + ((u >> 16) & 1);
  return u >> 16;
}

// ---------------- CSR build ----------------

__global__ __launch_bounds__(256) void k_zero(int* __restrict__ p, int n) {
  int i = blockIdx.x * 256 + threadIdx.x;
  if (i < n) p[i] = 0;
}

__global__ __launch_bounds__(256) void k_count(const int* __restrict__ dst, int* __restrict__ deg, int E) {
  int i = blockIdx.x * 256 + threadIdx.x;
  if (i < E) atomicAdd(&deg[dst[i]], 1);
}

__global__ __launch_bounds__(256) void k_dinv(const int* __restrict__ deg, float* __restrict__ dinv, int n) {
  int i = blockIdx.x * 256 + threadIdx.x;
  if (i < n) dinv[i] = rsqrtf((float)(deg[i] + 1));  // +1 self-loop
}

__global__ __launch_bounds__(1024) void k_scan1(const int* __restrict__ deg, int* __restrict__ excl,
                                                int* __restrict__ blocksum, int n) {
  __shared__ int sd[1024];
  int tid = threadIdx.x;
  int i = blockIdx.x * 1024 + tid;
  int v = (i < n) ? deg[i] : 0;
  int x = v;
  sd[tid] = x;
  __syncthreads();
  for (int off = 1; off < 1024; off <<= 1) {
    int t = (tid >= off) ? sd[tid - off] : 0;
    __syncthreads();
    x += t;
    sd[tid] = x;
    __syncthreads();
  }
  if (i < n) excl[i] = x - v;
  if (tid == 1023) blocksum[blockIdx.x] = x;
}

__global__ void k_scan2(int* __restrict__ blocksum, int nb) {  // 1 block, 64 threads; nb <= 64
  int lane = threadIdx.x;
  int v = (lane < nb) ? blocksum[lane] : 0;
  int orig = v;
  for (int off = 1; off < 64; off <<= 1) {
    int t = __shfl_up(v, off, 64);
    if (lane >= off) v += t;
  }
  if (lane < nb) blocksum[lane] = v - orig;
}

__global__ __launch_bounds__(256) void k_scan3(int* __restrict__ row_ptr, const int* __restrict__ blockoff,
                                               int* __restrict__ cursor, int n, int E) {
  int i = blockIdx.x * 256 + threadIdx.x;
  if (i < n) {
    int r = row_ptr[i] + blockoff[i >> 10];
    row_ptr[i] = r;
    cursor[i] = r;
  }
  if (i == 0) row_ptr[n] = E;
}

__global__ __launch_bounds__(256) void k_fill(const int* __restrict__ src, const int* __restrict__ dst,
                                              int* __restrict__ cursor, int* __restrict__ csr_src, int E) {
  int i = blockIdx.x * 256 + threadIdx.x;
  if (i < E) {
    int slot = atomicAdd(&cursor[dst[i]], 1);
    csr_src[slot] = src[i];
  }
}

// ---------------- dense GEMM: C[n x 128] = A[n x 128] @ W[128 x 128], bf16 out ----------------
// block = 256 threads, 32 rows; thread = 4 rows x 4 cols; k-blocked by 4 so A reads are b128.
template <typename TA>
__global__ __launch_bounds__(256) void k_gemm(const TA* __restrict__ A, const float* __restrict__ W,
                                              ushort* __restrict__ C, int n) {
  __shared__ float sW[CH * CH];   // 64 KB
  __shared__ float sA[32][CH];    // 16 KB
  for (int i = threadIdx.x; i < CH * CH / 4; i += 256)
    *(float4*)&sW[i * 4] = *(const float4*)&W[i * 4];

  int rb = blockIdx.x * 32;
  if constexpr (sizeof(TA) == 4) {  // fp32 input
    for (int i = threadIdx.x; i < 32 * 32; i += 256) {
      int r = i >> 5, c4 = (i & 31) << 2;
      int row = rb + r;
      float4 val = (row < n) ? *(const float4*)&A[(size_t)row * CH + c4]
                             : make_float4(0.f, 0.f, 0.f, 0.f);
      *(float4*)&sA[r][c4] = val;
    }
  } else {  // bf16 input
    for (int i = threadIdx.x; i < 32 * 16; i += 256) {
      int r = i >> 4, c8 = (i & 15) << 3;
      int row = rb + r;
      float* dstp = &sA[r][c8];
      if (row < n) {
        uint4 q = *(const uint4*)&A[(size_t)row * CH + c8];
        dstp[0] = bf_lo(q.x); dstp[1] = bf_hi(q.x);
        dstp[2] = bf_lo(q.y); dstp[3] = bf_hi(q.y);
        dstp[4] = bf_lo(q.z); dstp[5] = bf_hi(q.z);
        dstp[6] = bf_lo(q.w); dstp[7] = bf_hi(q.w);
      } else {
        for (int t = 0; t < 8; ++t) dstp[t] = 0.f;
      }
    }
  }
  __syncthreads();

  int tx = threadIdx.x & 31;   // cols tx*4 .. tx*4+3
  int ty = threadIdx.x >> 5;   // rows ty*4 .. ty*4+3
  float acc[4][4] = {};
  for (int k4 = 0; k4 < CH; k4 += 4) {
    float4 a[4], w[4];
#pragma unroll
    for (int j = 0; j < 4; ++j) a[j] = *(const float4*)&sA[(ty << 2) + j][k4];
#pragma unroll
    for (int kk = 0; kk < 4; ++kk) w[kk] = *(const float4*)&sW[(k4 + kk) * CH + (tx << 2)];
#pragma unroll
    for (int j = 0; j < 4; ++j) {
      const float aj[4] = {a[j].x, a[j].y, a[j].z, a[j].w};
#pragma unroll
      for (int kk = 0; kk < 4; ++kk) {
        acc[j][0] += aj[kk] * w[kk].x;
        acc[j][1] += aj[kk] * w[kk].y;
        acc[j][2] += aj[kk] * w[kk].z;
        acc[j][3] += aj[kk] * w[kk].w;
      }
    }
  }
#pragma unroll
  for (int r = 0; r < 4; ++r) {
    int row = rb + (ty << 2) + r;
    if (row < n) {
      uint2 o;
      o.x = f2bf(acc[r][0]) | (f2bf(acc[r][1]) << 16);
      o.y = f2bf(acc[r][2]) | (f2bf(acc[r][3]) << 16);
      *(uint2*)&C[(size_t)row * CH + (tx << 2)] = o;
    }
  }
}

// ---------------- aggregation: out[v] = relu(sum norm * h[s] + self + b) ----------------
// one wave64 per node, 2 adjacent channels per lane (one dword gather per lane per row).
template <bool OUT_BF16>
__global__ __launch_bounds__(256) void k_agg(const ushort* __restrict__ h, const int* __restrict__ row_ptr,
                                             const int* __restrict__ csr_src, const float* __restrict__ dinv,
                                             const float* __restrict__ b, void* __restrict__ outp, int n) {
  int v = (blockIdx.x * 256 + threadIdx.x) >> 6;
  int lane = threadIdx.x & 63;
  if (v >= n) return;
  v = __builtin_amdgcn_readfirstlane(v);
  float dv = dinv[v];
  uint32_t us = *(const uint32_t*)&h[(size_t)v * CH + 2 * lane];
  float self = dv * dv;
  float acc0 = bf_lo(us) * self;
  float acc1 = bf_hi(us) * self;
  int j = row_ptr[v], end = row_ptr[v + 1];
  for (; j + 3 < end; j += 4) {
    int s0 = csr_src[j], s1 = csr_src[j + 1], s2 = csr_src[j + 2], s3 = csr_src[j + 3];
    float w0 = dinv[s0] * dv, w1 = dinv[s1] * dv, w2 = dinv[s2] * dv, w3 = dinv[s3] * dv;
    uint32_t u0 = *(const uint32_t*)&h[(size_t)s0 * CH + 2 * lane];
    uint32_t u1 = *(const uint32_t*)&h[(size_t)s1 * CH + 2 * lane];
    uint32_t u2 = *(const uint32_t*)&h[(size_t)s2 * CH + 2 * lane];
    uint32_t u3 = *(const uint32_t*)&h[(size_t)s3 * CH + 2 * lane];
    acc0 += bf_lo(u0) * w0; acc1 += bf_hi(u0) * w0;
    acc0 += bf_lo(u1) * w1; acc1 += bf_hi(u1) * w1;
    acc0 += bf_lo(u2) * w2; acc1 += bf_hi(u2) * w2;
    acc0 += bf_lo(u3) * w3; acc1 += bf_hi(u3) * w3;
  }
  for (; j < end; ++j) {
    int s0 = csr_src[j];
    float w0 = dinv[s0] * dv;
    uint32_t u0 = *(const uint32_t*)&h[(size_t)s0 * CH + 2 * lane];
    acc0 += bf_lo(u0) * w0; acc1 += bf_hi(u0) * w0;
  }
  float2 bb = *(const float2*)&b[2 * lane];
  acc0 = fmaxf(acc0 + bb.x, 0.f);
  acc1 = fmaxf(acc1 + bb.y, 0.f);
  if constexpr (OUT_BF16) {
    ((uint32_t*)outp)[(size_t)v * 64 + lane] = f2bf(acc0) | (f2bf(acc1) << 16);
  } else {
    ((float2*)outp)[(size_t)v * 64 + lane] = make_float2(acc0, acc1);
  }
}

// ---------------- launch ----------------

extern "C" void kernel_launch(void* const* d_in, const int* in_sizes, int n_in,
                              void* d_out, int out_size, void* d_ws, size_t ws_size,
                              hipStream_t stream) {
  const float* x  = (const float*)d_in[0];
  const int*   ei = (const int*)d_in[1];
  const float* W1 = (const float*)d_in[2];
  const float* b1 = (const float*)d_in[3];
  const float* W2 = (const float*)d_in[4];
  const float* b2 = (const float*)d_in[5];
  float* out = (float*)d_out;

  const int N = in_sizes[0] / CH;
  const int E = in_sizes[1] / 2;
  const int* src = ei;
  const int* dst = ei + E;

  char* ws = (char*)d_ws;
  size_t off = 0;
  auto alloc = [&](size_t bytes) -> void* {
    void* p = ws + off;
    off += (bytes + 255) & ~(size_t)255;
    return p;
  };
  int*    deg      = (int*)alloc((size_t)N * 4);
  int*    row_ptr  = (int*)alloc((size_t)(N + 1) * 4);
  int*    cursor   = (int*)alloc((size_t)N * 4);
  int*    csr_src  = (int*)alloc((size_t)E * 4);
  int*    blocksum = (int*)alloc(64 * 4);
  float*  dinv     = (float*)alloc((size_t)N * 4);
  ushort* h        = (ushort*)alloc((size_t)N * CH * 2);  // bf16
  ushort* y1       = (ushort*)alloc((size_t)N * CH * 2);  // bf16
  (void)ws_size;

  const int gN = (N + 255) / 256;
  const int gE = (E + 255) / 256;
  const int nb = (N + 1023) / 1024;

  k_zero<<<gN, 256, 0, stream>>>(deg, N);
  k_count<<<gE, 256, 0, stream>>>(dst, deg, E);
  k_dinv<<<gN, 256, 0, stream>>>(deg, dinv, N);
  k_scan1<<<nb, 1024, 0, stream>>>(deg, row_ptr, blocksum, N);
  k_scan2<<<1, 64, 0, stream>>>(blocksum, nb);
  k_scan3<<<gN, 256, 0, stream>>>(row_ptr, blocksum, cursor, N, E);
  k_fill<<<gE, 256, 0, stream>>>(src, dst, cursor, csr_src, E);

  const int gG = (N + 31) / 32;
  const int gA = (N + 3) / 4;

  // layer 1
  k_gemm<float><<<gG, 256, 0, stream>>>(x, W1, h, N);
  k_agg<true><<<gA, 256, 0, stream>>>(h, row_ptr, csr_src, dinv, b1, y1, N);
  // layer 2
  k_gemm<ushort><<<gG, 256, 0, stream>>>(y1, W2, h, N);
  k_agg<false><<<gA, 256, 0, stream>>>(h, row_ptr, csr_src, dinv, b2, out, N);
}

// Round 3
// 183.917 us; speedup vs baseline: 1.4480x; 1.1790x over previous
//
#include <hip/hip_runtime.h>
#include <hip/hip_bf16.h>
#include <cstdint>

#define CH 128

typedef __attribute__((ext_vector_type(8))) short short8;
typedef __attribute__((ext_vector_type(4))) float f32x4;

union FragU {
  uint4 u;
  short8 s;
  ushort h[8];
};

// ---------------- bf16 helpers ----------------
__device__ __forceinline__ float bf_lo(uint32_t u) { return __uint_as_float(u << 16); }
__device__ __forceinline__ float bf_hi(uint32_t u) { return __uint_as_float(u & 0xffff0000u); }
__device__ __forceinline__ uint32_t f2bf(float f) {  // RNE, result in low 16
  uint32_t u = __float_as_uint(f);
  u += 0x7fff + ((u >> 16) & 1);
  return u >> 16;
}

// ---------------- CSR build ----------------

__global__ __launch_bounds__(256) void k_zero(int* __restrict__ p, int n) {
  int i = blockIdx.x * 256 + threadIdx.x;
  if (i < n) p[i] = 0;
}

__global__ __launch_bounds__(256) void k_count(const int* __restrict__ dst, int* __restrict__ deg, int E) {
  int i = blockIdx.x * 256 + threadIdx.x;
  if (i < E) atomicAdd(&deg[dst[i]], 1);
}

__global__ __launch_bounds__(256) void k_dinv(const int* __restrict__ deg, float* __restrict__ dinv, int n) {
  int i = blockIdx.x * 256 + threadIdx.x;
  if (i < n) dinv[i] = rsqrtf((float)(deg[i] + 1));  // +1 self-loop
}

__global__ __launch_bounds__(1024) void k_scan1(const int* __restrict__ deg, int* __restrict__ excl,
                                                int* __restrict__ blocksum, int n) {
  __shared__ int sd[1024];
  int tid = threadIdx.x;
  int i = blockIdx.x * 1024 + tid;
  int v = (i < n) ? deg[i] : 0;
  int x = v;
  sd[tid] = x;
  __syncthreads();
  for (int off = 1; off < 1024; off <<= 1) {
    int t = (tid >= off) ? sd[tid - off] : 0;
    __syncthreads();
    x += t;
    sd[tid] = x;
    __syncthreads();
  }
  if (i < n) excl[i] = x - v;
  if (tid == 1023) blocksum[blockIdx.x] = x;
}

__global__ void k_scan2(int* __restrict__ blocksum, int nb) {  // 1 block, 64 threads; nb <= 64
  int lane = threadIdx.x;
  int v = (lane < nb) ? blocksum[lane] : 0;
  int orig = v;
  for (int off = 1; off < 64; off <<= 1) {
    int t = __shfl_up(v, off, 64);
    if (lane >= off) v += t;
  }
  if (lane < nb) blocksum[lane] = v - orig;
}

__global__ __launch_bounds__(256) void k_scan3(int* __restrict__ row_ptr, const int* __restrict__ blockoff,
                                               int* __restrict__ cursor, int n, int E) {
  int i = blockIdx.x * 256 + threadIdx.x;
  if (i < n) {
    int r = row_ptr[i] + blockoff[i >> 10];
    row_ptr[i] = r;
    cursor[i] = r;
  }
  if (i == 0) row_ptr[n] = E;
}

__global__ __launch_bounds__(256) void k_fill(const int* __restrict__ src, const int* __restrict__ dst,
                                              int* __restrict__ cursor, int* __restrict__ csr_src, int E) {
  int i = blockIdx.x * 256 + threadIdx.x;
  if (i < E) {
    int slot = atomicAdd(&cursor[dst[i]], 1);
    csr_src[slot] = src[i];
  }
}

// ---------------- W pre-pack into MFMA fragment order (hi/lo bf16) ----------------
// buf layout: [hi1 | lo1 | hi2 | lo2], each 16384 u16.
// Fragment (j = n/16, t = k/32): 64 lanes x 8 elems; lane = (n&15) | (((k>>3)&3)<<4), elem i = k&7.
__global__ __launch_bounds__(256) void k_wpack(const float* __restrict__ W1, const float* __restrict__ W2,
                                               ushort* __restrict__ buf) {
  int which = blockIdx.x >> 6;
  int idx = (blockIdx.x & 63) * 256 + threadIdx.x;  // 0..16383
  const float* W = which ? W2 : W1;
  ushort* hi = buf + which * 32768;
  ushort* lo = hi + 16384;
  int k = idx >> 7, n = idx & 127;
  float w = W[idx];
  uint32_t hb = f2bf(w);
  uint32_t lb = f2bf(w - bf_lo(hb));
  int j = n >> 4, t = k >> 5, ln = (n & 15) | (((k >> 3) & 3) << 4), i = k & 7;
  int p = (j * 4 + t) * 512 + ln * 8 + i;
  hi[p] = (ushort)hb;
  lo[p] = (ushort)lb;
}

// ---------------- MFMA GEMM: C[n x 128] = A[n x 128] @ W[128 x 128] ----------------
// One wave handles 32 rows (2 tiles of 16). No LDS, no barriers. W fragments from
// L2-resident packed buffer. mfma(Wfrag, Afrag, acc) => lane stores 4 consecutive cols.
template <typename TA, bool OUT_BF16>
__global__ __launch_bounds__(256) void k_gemm_mfma(const TA* __restrict__ A,
                                                   const ushort* __restrict__ wpack,
                                                   void* __restrict__ Cp, int n) {
  const int lane = threadIdx.x & 63;
  const int gwave = (blockIdx.x * 256 + threadIdx.x) >> 6;
  const int rb = gwave * 32;
  if (rb >= n) return;
  const int lrow = lane & 15, lgrp = lane >> 4;
  const uint4* whi4 = (const uint4*)wpack;             // 32 frags * 64 lanes * 16B
  const uint4* wlo4 = (const uint4*)(wpack + 16384);

  const int r0 = rb + lrow, r1 = rb + 16 + lrow;
  const bool v0 = r0 < n, v1 = r1 < n;
  const int rc0 = v0 ? r0 : 0, rc1 = v1 ? r1 : 0;

  f32x4 acc0[8] = {};
  f32x4 acc1[8] = {};
  const uint4 zz = make_uint4(0, 0, 0, 0);

#pragma unroll
  for (int t = 0; t < 4; ++t) {
    FragU a0h, a0l, a1h, a1l;
    if constexpr (sizeof(TA) == 4) {  // fp32 input -> hi/lo split
      const float* ap0 = (const float*)A + (size_t)rc0 * CH + t * 32 + lgrp * 8;
      const float* ap1 = (const float*)A + (size_t)rc1 * CH + t * 32 + lgrp * 8;
      float4 xa = *(const float4*)ap0, xb = *(const float4*)(ap0 + 4);
      float4 ya = *(const float4*)ap1, yb = *(const float4*)(ap1 + 4);
      float xv[8] = {xa.x, xa.y, xa.z, xa.w, xb.x, xb.y, xb.z, xb.w};
      float yv[8] = {ya.x, ya.y, ya.z, ya.w, yb.x, yb.y, yb.z, yb.w};
#pragma unroll
      for (int i = 0; i < 8; ++i) {
        uint32_t h0 = f2bf(xv[i]);
        a0h.h[i] = (ushort)h0;
        a0l.h[i] = (ushort)f2bf(xv[i] - bf_lo(h0));
        uint32_t h1 = f2bf(yv[i]);
        a1h.h[i] = (ushort)h1;
        a1l.h[i] = (ushort)f2bf(yv[i] - bf_lo(h1));
      }
      if (!v0) { a0h.u = zz; a0l.u = zz; }
      if (!v1) { a1h.u = zz; a1l.u = zz; }
    } else {  // bf16 input
      a0h.u = v0 ? *(const uint4*)((const ushort*)A + (size_t)rc0 * CH + t * 32 + lgrp * 8) : zz;
      a1h.u = v1 ? *(const uint4*)((const ushort*)A + (size_t)rc1 * CH + t * 32 + lgrp * 8) : zz;
    }
#pragma unroll
    for (int j = 0; j < 8; ++j) {
      FragU wh, wl;
      wh.u = whi4[(j * 4 + t) * 64 + lane];
      wl.u = wlo4[(j * 4 + t) * 64 + lane];
      acc0[j] = __builtin_amdgcn_mfma_f32_16x16x32_bf16(wh.s, a0h.s, acc0[j], 0, 0, 0);
      acc0[j] = __builtin_amdgcn_mfma_f32_16x16x32_bf16(wl.s, a0h.s, acc0[j], 0, 0, 0);
      acc1[j] = __builtin_amdgcn_mfma_f32_16x16x32_bf16(wh.s, a1h.s, acc1[j], 0, 0, 0);
      acc1[j] = __builtin_amdgcn_mfma_f32_16x16x32_bf16(wl.s, a1h.s, acc1[j], 0, 0, 0);
      if constexpr (sizeof(TA) == 4) {
        acc0[j] = __builtin_amdgcn_mfma_f32_16x16x32_bf16(wh.s, a0l.s, acc0[j], 0, 0, 0);
        acc1[j] = __builtin_amdgcn_mfma_f32_16x16x32_bf16(wh.s, a1l.s, acc1[j], 0, 0, 0);
      }
    }
  }

  // store: lane holds C[r][j*16 + lgrp*4 .. +3]
  if (v0) {
#pragma unroll
    for (int j = 0; j < 8; ++j) {
      if constexpr (OUT_BF16) {
        uint2 o;
        o.x = f2bf(acc0[j][0]) | (f2bf(acc0[j][1]) << 16);
        o.y = f2bf(acc0[j][2]) | (f2bf(acc0[j][3]) << 16);
        *(uint2*)&((ushort*)Cp)[(size_t)r0 * CH + j * 16 + lgrp * 4] = o;
      } else {
        float4 o = make_float4(acc0[j][0], acc0[j][1], acc0[j][2], acc0[j][3]);
        *(float4*)&((float*)Cp)[(size_t)r0 * CH + j * 16 + lgrp * 4] = o;
      }
    }
  }
  if (v1) {
#pragma unroll
    for (int j = 0; j < 8; ++j) {
      if constexpr (OUT_BF16) {
        uint2 o;
        o.x = f2bf(acc1[j][0]) | (f2bf(acc1[j][1]) << 16);
        o.y = f2bf(acc1[j][2]) | (f2bf(acc1[j][3]) << 16);
        *(uint2*)&((ushort*)Cp)[(size_t)r1 * CH + j * 16 + lgrp * 4] = o;
      } else {
        float4 o = make_float4(acc1[j][0], acc1[j][1], acc1[j][2], acc1[j][3]);
        *(float4*)&((float*)Cp)[(size_t)r1 * CH + j * 16 + lgrp * 4] = o;
      }
    }
  }
}

// ---------------- aggregation: out[v] = relu(sum norm * h[s] + self + b) ----------------
template <bool OUT_BF16>
__global__ __launch_bounds__(256) void k_agg(const ushort* __restrict__ h, const int* __restrict__ row_ptr,
                                             const int* __restrict__ csr_src, const float* __restrict__ dinv,
                                             const float* __restrict__ b, void* __restrict__ outp, int n) {
  int v = (blockIdx.x * 256 + threadIdx.x) >> 6;
  int lane = threadIdx.x & 63;
  if (v >= n) return;
  v = __builtin_amdgcn_readfirstlane(v);
  float dv = dinv[v];
  uint32_t us = *(const uint32_t*)&h[(size_t)v * CH + 2 * lane];
  float self = dv * dv;
  float acc0 = bf_lo(us) * self;
  float acc1 = bf_hi(us) * self;
  int j = row_ptr[v], end = row_ptr[v + 1];
  for (; j + 3 < end; j += 4) {
    int s0 = csr_src[j], s1 = csr_src[j + 1], s2 = csr_src[j + 2], s3 = csr_src[j + 3];
    float w0 = dinv[s0] * dv, w1 = dinv[s1] * dv, w2 = dinv[s2] * dv, w3 = dinv[s3] * dv;
    uint32_t u0 = *(const uint32_t*)&h[(size_t)s0 * CH + 2 * lane];
    uint32_t u1 = *(const uint32_t*)&h[(size_t)s1 * CH + 2 * lane];
    uint32_t u2 = *(const uint32_t*)&h[(size_t)s2 * CH + 2 * lane];
    uint32_t u3 = *(const uint32_t*)&h[(size_t)s3 * CH + 2 * lane];
    acc0 += bf_lo(u0) * w0; acc1 += bf_hi(u0) * w0;
    acc0 += bf_lo(u1) * w1; acc1 += bf_hi(u1) * w1;
    acc0 += bf_lo(u2) * w2; acc1 += bf_hi(u2) * w2;
    acc0 += bf_lo(u3) * w3; acc1 += bf_hi(u3) * w3;
  }
  for (; j < end; ++j) {
    int s0 = csr_src[j];
    float w0 = dinv[s0] * dv;
    uint32_t u0 = *(const uint32_t*)&h[(size_t)s0 * CH + 2 * lane];
    acc0 += bf_lo(u0) * w0; acc1 += bf_hi(u0) * w0;
  }
  float2 bb = *(const float2*)&b[2 * lane];
  acc0 = fmaxf(acc0 + bb.x, 0.f);
  acc1 = fmaxf(acc1 + bb.y, 0.f);
  if constexpr (OUT_BF16) {
    ((uint32_t*)outp)[(size_t)v * 64 + lane] = f2bf(acc0) | (f2bf(acc1) << 16);
  } else {
    ((float2*)outp)[(size_t)v * 64 + lane] = make_float2(acc0, acc1);
  }
}

// ---------------- launch ----------------

extern "C" void kernel_launch(void* const* d_in, const int* in_sizes, int n_in,
                              void* d_out, int out_size, void* d_ws, size_t ws_size,
                              hipStream_t stream) {
  const float* x  = (const float*)d_in[0];
  const int*   ei = (const int*)d_in[1];
  const float* W1 = (const float*)d_in[2];
  const float* b1 = (const float*)d_in[3];
  const float* W2 = (const float*)d_in[4];
  const float* b2 = (const float*)d_in[5];
  float* out = (float*)d_out;

  const int N = in_sizes[0] / CH;
  const int E = in_sizes[1] / 2;
  const int* src = ei;
  const int* dst = ei + E;

  char* ws = (char*)d_ws;
  size_t off = 0;
  auto alloc = [&](size_t bytes) -> void* {
    void* p = ws + off;
    off += (bytes + 255) & ~(size_t)255;
    return p;
  };
  int*    deg      = (int*)alloc((size_t)N * 4);
  int*    row_ptr  = (int*)alloc((size_t)(N + 1) * 4);
  int*    cursor   = (int*)alloc((size_t)N * 4);
  int*    csr_src  = (int*)alloc((size_t)E * 4);
  int*    blocksum = (int*)alloc(64 * 4);
  float*  dinv     = (float*)alloc((size_t)N * 4);
  ushort* wpack    = (ushort*)alloc(4 * 16384 * 2);   // [hi1|lo1|hi2|lo2]
  ushort* h        = (ushort*)alloc((size_t)N * CH * 2);  // bf16
  ushort* y1       = (ushort*)alloc((size_t)N * CH * 2);  // bf16
  (void)ws_size;

  const int gN = (N + 255) / 256;
  const int gE = (E + 255) / 256;
  const int nb = (N + 1023) / 1024;

  k_zero<<<gN, 256, 0, stream>>>(deg, N);
  k_count<<<gE, 256, 0, stream>>>(dst, deg, E);
  k_dinv<<<gN, 256, 0, stream>>>(deg, dinv, N);
  k_scan1<<<nb, 1024, 0, stream>>>(deg, row_ptr, blocksum, N);
  k_scan2<<<1, 64, 0, stream>>>(blocksum, nb);
  k_scan3<<<gN, 256, 0, stream>>>(row_ptr, blocksum, cursor, N, E);
  k_fill<<<gE, 256, 0, stream>>>(src, dst, cursor, csr_src, E);
  k_wpack<<<128, 256, 0, stream>>>(W1, W2, wpack);

  const int waves = (N + 31) / 32;
  const int gG = (waves + 3) / 4;        // 4 waves per block
  const int gA = (N + 3) / 4;

  // layer 1
  k_gemm_mfma<float, true><<<gG, 256, 0, stream>>>(x, wpack, h, N);
  k_agg<true><<<gA, 256, 0, stream>>>(h, row_ptr, csr_src, dinv, b1, y1, N);
  // layer 2
  k_gemm_mfma<ushort, true><<<gG, 256, 0, stream>>>(y1, wpack + 32768, h, N);
  k_agg<false><<<gA, 256, 0, stream>>>(h, row_ptr, csr_src, dinv, b2, out, N);
}